// Round 8
// baseline (1210.149 us; speedup 1.0000x reference)
//
#include <hip/hip_runtime.h>
#include <hip/hip_fp16.h>

#define FD 128          // feature dim
#define RPB 4           // rows (waves) per block; block = 256 threads
// NOTE: algebraic elimination of b_{M-1} assumes M >= 4 (here M = 30).

// ---------------- CSR build ----------------

__global__ void zero_i32(int* __restrict__ p, int n) {
  int i = blockIdx.x * blockDim.x + threadIdx.x;
  if (i < n) p[i] = 0;
}

__global__ void hist_kernel(const int* __restrict__ rows, int* __restrict__ cnt, int nnz) {
  int i = blockIdx.x * blockDim.x + threadIdx.x;
  if (i < nnz) atomicAdd(&cnt[rows[i]], 1);
}

// coalesced 3-phase scan
__global__ void block_reduce(const int* __restrict__ cnt, int* __restrict__ bsum, int n) {
  __shared__ int sm[256];
  int i = blockIdx.x * 256 + threadIdx.x;
  sm[threadIdx.x] = (i < n) ? cnt[i] : 0;
  __syncthreads();
  for (int off = 128; off > 0; off >>= 1) {
    if (threadIdx.x < off) sm[threadIdx.x] += sm[threadIdx.x + off];
    __syncthreads();
  }
  if (threadIdx.x == 0) bsum[blockIdx.x] = sm[0];
}

__global__ void scan_bsum(const int* __restrict__ bsum, int* __restrict__ bpre, int nb) {
  __shared__ int sm[1024];
  const int tid = threadIdx.x;
  sm[tid] = (tid < nb) ? bsum[tid] : 0;
  __syncthreads();
  for (int off = 1; off < 1024; off <<= 1) {
    int t = (tid >= off) ? sm[tid - off] : 0;
    __syncthreads();
    sm[tid] += t;
    __syncthreads();
  }
  if (tid < nb) bpre[tid] = (tid == 0) ? 0 : sm[tid - 1];
}

__global__ void block_scan(const int* __restrict__ cnt, const int* __restrict__ bpre,
                           int* __restrict__ row_ptr, int n) {
  __shared__ int sm[256];
  const int tid = threadIdx.x;
  int i = blockIdx.x * 256 + tid;
  sm[tid] = (i < n) ? cnt[i] : 0;
  __syncthreads();
  for (int off = 1; off < 256; off <<= 1) {
    int t = (tid >= off) ? sm[tid - off] : 0;
    __syncthreads();
    sm[tid] += t;
    __syncthreads();
  }
  if (i < n) row_ptr[i + 1] = sm[tid] + bpre[blockIdx.x];
  if (i == 0) row_ptr[0] = 0;
}

__global__ void copy_i32(const int* __restrict__ src, int* __restrict__ dst, int n) {
  int i = blockIdx.x * blockDim.x + threadIdx.x;
  if (i < n) dst[i] = src[i];
}

// packed edge scatter: one 8B store per edge; also writes a 32-entry zero pad
// so the step kernels' prefetch can run unclamped past `end`.
__global__ void scatter_kernel(const int* __restrict__ rows, const int* __restrict__ cols,
                               const float* __restrict__ vals, int* __restrict__ fill,
                               int2* __restrict__ pk, int nnz) {
  int i = blockIdx.x * blockDim.x + threadIdx.x;
  if (i < 32) pk[nnz + i] = make_int2(0, 0);
  if (i < nnz) {
    int r = rows[i];
    int pos = atomicAdd(&fill[r], 1);
    pk[pos] = make_int2(cols[i], __float_as_int(vals[i]));
  }
}

__global__ void f32_to_f16(const float* __restrict__ src, __half* __restrict__ dst, int n4) {
  int i = blockIdx.x * blockDim.x + threadIdx.x;
  if (i < n4) {
    float4 v = ((const float4*)src)[i];
    __half2* d = (__half2*)dst + 2 * (size_t)i;
    d[0] = __floats2half2_rn(v.x, v.y);
    d[1] = __floats2half2_rn(v.z, v.w);
  }
}

// ---------------- wide, phase-split gather ----------------
// Wave = 1 row. sub = lane>>4 picks 1 of 4 edges/round; fl = lane&15 picks an
// 8-feature quad (uint4). Phase 1: ALL edge int2s for the row (independent).
// Phase 2: ALL feature vectors (independent given phase 1). Phase 3: FMA.
// This collapses the per-row dependent chain to ~2 memory rounds.

__device__ __forceinline__ void fma4(const uint4& raw, float v, float2 acc[4]) {
  const __half2* h = (const __half2*)&raw;
  float2 x0 = __half22float2(h[0]);
  float2 x1 = __half22float2(h[1]);
  float2 x2 = __half22float2(h[2]);
  float2 x3 = __half22float2(h[3]);
  acc[0].x = fmaf(v, x0.x, acc[0].x); acc[0].y = fmaf(v, x0.y, acc[0].y);
  acc[1].x = fmaf(v, x1.x, acc[1].x); acc[1].y = fmaf(v, x1.y, acc[1].y);
  acc[2].x = fmaf(v, x2.x, acc[2].x); acc[2].y = fmaf(v, x2.y, acc[2].y);
  acc[3].x = fmaf(v, x3.x, acc[3].x); acc[3].y = fmaf(v, x3.y, acc[3].y);
}

__device__ __forceinline__ void gather_row(const int* __restrict__ rp,
                                           const int2* __restrict__ pk,
                                           const __half* __restrict__ T,
                                           int r, int sub, int fl, float2 acc[4]) {
  const int e0 = rp[r];
  const int end = rp[r + 1];
  const int d = end - e0;
  const int rounds = min((d + 3) >> 2, 8);   // wave-uniform
  int2 cv[8];
  uint4 xr[8];
#pragma unroll
  for (int j = 0; j < 8; ++j)
    if (j < rounds) cv[j] = pk[e0 + 4 * j + sub];        // all independent
#pragma unroll
  for (int j = 0; j < 8; ++j)
    if (j < rounds) xr[j] = ((const uint4*)(T + (size_t)cv[j].x * FD))[fl];
#pragma unroll
  for (int j = 0; j < 8; ++j)
    if (j < rounds) {
      float v = (4 * j + sub < d) ? __int_as_float(cv[j].y) : 0.f;
      fma4(xr[j], v, acc);
    }
  // rare tail: degree > 32 (P ~ 1e-4 at avg degree 16)
  for (int e = e0 + 32; e < end; e += 4) {
    int idx = e + sub;                       // pad-safe: pk has 32 zero entries
    int2 c = pk[idx];
    float v = (idx < end) ? __int_as_float(c.y) : 0.f;
    uint4 x = ((const uint4*)(T + (size_t)c.x * FD))[fl];
    fma4(x, v, acc);
  }
}

__device__ __forceinline__ void reduce_subs(float2 acc[4]) {
#pragma unroll
  for (int m = 16; m < 64; m <<= 1) {
#pragma unroll
    for (int q = 0; q < 4; ++q) {
      acc[q].x += __shfl_xor(acc[q].x, m, 64);
      acc[q].y += __shfl_xor(acc[q].y, m, 64);
    }
  }
}

// ---------------- Clenshaw steps ----------------
// b_k = 2*gs*(L @ src) - p + ck_eff * X   (fp16 state, fp32 math)
// flags: bit0 = read p from pd; bit1 = ck_eff = c_k - c_{M-1} (folds b_{M-1});
//        bit2 = gs = c_{M-1} (src is Xh standing in for b_{M-1} = c_{M-1} X).
// pd holds b_{k+2} and receives b_k (same element, same lane -> safe in-place).

__global__ __launch_bounds__(256) void clen_step(
    const int* __restrict__ rp, const int2* __restrict__ pk,
    const __half* __restrict__ src, const __half* __restrict__ Xh, __half* pd,
    const float* __restrict__ coeffs, int k, int flags, int M, int n) {
  const int lane = threadIdx.x & 63;
  const int sub = lane >> 4, fl = lane & 15;
  const int r = blockIdx.x * RPB + (threadIdx.x >> 6);
  if (r >= n) return;
  float2 acc[4] = {{0.f,0.f},{0.f,0.f},{0.f,0.f},{0.f,0.f}};
  gather_row(rp, pk, src, r, sub, fl, acc);
  reduce_subs(acc);
  if (sub == 0) {
    float ck = coeffs[k];
    if (flags & 2) ck -= coeffs[M - 1];
    const float g2 = (flags & 4) ? 2.f * coeffs[M - 1] : 2.f;
    uint4 xr = ((const uint4*)(Xh + (size_t)r * FD))[fl];
    const __half2* xh = (const __half2*)&xr;
    float2 p[4] = {{0.f,0.f},{0.f,0.f},{0.f,0.f},{0.f,0.f}};
    if (flags & 1) {
      uint4 pr = ((const uint4*)(pd + (size_t)r * FD))[fl];
      const __half2* ph = (const __half2*)&pr;
#pragma unroll
      for (int q = 0; q < 4; ++q) p[q] = __half22float2(ph[q]);
    }
    uint4 orr;
    __half2* oh = (__half2*)&orr;
#pragma unroll
    for (int q = 0; q < 4; ++q) {
      float2 x = __half22float2(xh[q]);
      float tx = fmaf(g2, acc[q].x, fmaf(ck, x.x, -p[q].x));
      float ty = fmaf(g2, acc[q].y, fmaf(ck, x.y, -p[q].y));
      oh[q] = __floats2half2_rn(tx, ty);
    }
    ((uint4*)(pd + (size_t)r * FD))[fl] = orr;
  }
}

// out = c0*X + L @ b1 - b2   (fp32 X and output)
__global__ __launch_bounds__(256) void clen_final(
    const int* __restrict__ rp, const int2* __restrict__ pk,
    const __half* __restrict__ b1, const __half* __restrict__ b2,
    const float* __restrict__ X, float* __restrict__ out,
    const float* __restrict__ coeffs, int n) {
  const int lane = threadIdx.x & 63;
  const int sub = lane >> 4, fl = lane & 15;
  const int r = blockIdx.x * RPB + (threadIdx.x >> 6);
  if (r >= n) return;
  float2 acc[4] = {{0.f,0.f},{0.f,0.f},{0.f,0.f},{0.f,0.f}};
  gather_row(rp, pk, b1, r, sub, fl, acc);
  reduce_subs(acc);
  if (sub == 0) {
    const float c0 = coeffs[0];
    uint4 pr = ((const uint4*)(b2 + (size_t)r * FD))[fl];
    const __half2* ph = (const __half2*)&pr;
    float4 x0 = ((const float4*)(X + (size_t)r * FD))[fl * 2];
    float4 x1 = ((const float4*)(X + (size_t)r * FD))[fl * 2 + 1];
    float2 p0 = __half22float2(ph[0]), p1 = __half22float2(ph[1]);
    float2 p2 = __half22float2(ph[2]), p3 = __half22float2(ph[3]);
    float4 o0, o1;
    o0.x = fmaf(c0, x0.x, acc[0].x - p0.x);
    o0.y = fmaf(c0, x0.y, acc[0].y - p0.y);
    o0.z = fmaf(c0, x0.z, acc[1].x - p1.x);
    o0.w = fmaf(c0, x0.w, acc[1].y - p1.y);
    o1.x = fmaf(c0, x1.x, acc[2].x - p2.x);
    o1.y = fmaf(c0, x1.y, acc[2].y - p2.y);
    o1.z = fmaf(c0, x1.z, acc[3].x - p3.x);
    o1.w = fmaf(c0, x1.w, acc[3].y - p3.y);
    ((float4*)(out + (size_t)r * FD))[fl * 2] = o0;
    ((float4*)(out + (size_t)r * FD))[fl * 2 + 1] = o1;
  }
}

// ---------------- launch ----------------

extern "C" void kernel_launch(void* const* d_in, const int* in_sizes, int n_in,
                              void* d_out, int out_size, void* d_ws, size_t ws_size,
                              hipStream_t stream) {
  const int* rows = (const int*)d_in[0];
  const int* cols = (const int*)d_in[1];
  const float* vals = (const float*)d_in[2];
  const float* X = (const float*)d_in[3];
  const float* coeffs = (const float*)d_in[4];
  float* out = (float*)d_out;

  const int nnz = in_sizes[0];
  const int n = in_sizes[3] / FD;
  const int M = in_sizes[4];

  auto align_up = [](size_t x) { return (x + 255) & ~(size_t)255; };
  char* w = (char*)d_ws;
  size_t off = 0;
  int* row_ptr = (int*)(w + off); off = align_up(off + (size_t)(n + 1) * 4);
  int* row_fill = (int*)(w + off); off = align_up(off + (size_t)n * 4);
  int* bsum = (int*)(w + off); off = align_up(off + 1024 * 4);
  int* bpre = (int*)(w + off); off = align_up(off + 1024 * 4);
  int2* pk = (int2*)(w + off); off = align_up(off + ((size_t)nnz + 32) * 8);
  __half* Xh = (__half*)(w + off); off = align_up(off + (size_t)n * FD * 2);
  __half* buf0 = (__half*)(w + off); off = align_up(off + (size_t)n * FD * 2);
  __half* buf1 = (__half*)(w + off); off = align_up(off + (size_t)n * FD * 2);
  __half* bufs[2] = {buf0, buf1};
  (void)ws_size;

  const int B = 256;
  const int gN = (n + B - 1) / B;
  const int gE = (nnz + B - 1) / B;
  const int gS = (n + RPB - 1) / RPB;
  const int n4 = n * FD / 4;
  const int gC = (n4 + B - 1) / B;

  // CSR build
  zero_i32<<<gN, B, 0, stream>>>(row_fill, n);
  hist_kernel<<<gE, B, 0, stream>>>(rows, row_fill, nnz);
  block_reduce<<<gN, B, 0, stream>>>(row_fill, bsum, n);
  scan_bsum<<<1, 1024, 0, stream>>>(bsum, bpre, gN);
  block_scan<<<gN, B, 0, stream>>>(row_fill, bpre, row_ptr, n);
  copy_i32<<<gN, B, 0, stream>>>(row_ptr, row_fill, n);
  scatter_kernel<<<gE, B, 0, stream>>>(rows, cols, vals, row_fill, pk, nnz);
  f32_to_f16<<<gC, B, 0, stream>>>(X, Xh, n4);

  // Clenshaw (b_{M-1} = c_{M-1} X eliminated algebraically):
  // k = M-2: b = 2 c_{M-1} (L Xh) + c_{M-2} X            [flags = 4]
  // k = M-3: b = 2 (L b_{M-2}) + (c_{M-3} - c_{M-1}) X   [flags = 2]
  // k = M-4..1: b = 2 (L b_{k+1}) - b_{k+2} + c_k X      [flags = 1]
  // out = c0 X + L b1 - b2
  clen_step<<<gS, B, 0, stream>>>(row_ptr, pk, Xh, Xh, bufs[(M - 2) & 1],
                                  coeffs, M - 2, 4, M, n);
  clen_step<<<gS, B, 0, stream>>>(row_ptr, pk, bufs[(M - 2) & 1], Xh, bufs[(M - 3) & 1],
                                  coeffs, M - 3, 2, M, n);
  for (int k = M - 4; k >= 1; --k) {
    clen_step<<<gS, B, 0, stream>>>(row_ptr, pk, bufs[(k + 1) & 1], Xh, bufs[k & 1],
                                    coeffs, k, 1, M, n);
  }
  clen_final<<<gS, B, 0, stream>>>(row_ptr, pk, bufs[1], bufs[0], X, out, coeffs, n);
}